// Round 8
// baseline (2933.921 us; speedup 1.0000x reference)
//
#include <hip/hip_runtime.h>
#include <math.h>

#define N_NODES 100000
#define E_EDGES 3200000
#define IN_DIM_ 128
#define HID_ 64
#define BN_EPS_ 1e-5f

#define PB 200            // edge-chunk blocks for build
#define CHUNK 16000       // E / PB exactly
#define NBUCK 782         // ceil(N / 128): bucket = dst >> 7 (128 nodes/bucket)
#define BN_ 128           // nodes per bucket

#define CCH 6             // src chunks for locality sweep
#define CNODES 16667      // ceil(N / CCH)
#define CPS 100112        // stride of cp arrays (>= NBUCK*128 = 100096)

typedef __attribute__((ext_vector_type(8))) short short8;
typedef __attribute__((ext_vector_type(4))) float f32x4;

__device__ inline ushort f2bf(float f) {
    union { float f; unsigned u; } c; c.f = f;
    unsigned r = c.u + 0x7fff + ((c.u >> 16) & 1);   // RNE
    return (ushort)(r >> 16);
}
__device__ inline float bf2f(ushort s) {
    union { unsigned u; float f; } c; c.u = ((unsigned)s) << 16; return c.f;
}

// ---------------- pass A1: per-block bucket histogram ----------------
__global__ __launch_bounds__(256) void passA1_hist(const int* __restrict__ ei,
                                                   int* __restrict__ histPB) {
    __shared__ int hist[NBUCK];
    int t = threadIdx.x, b = blockIdx.x;
    for (int k = t; k < NBUCK; k += 256) hist[k] = 0;
    __syncthreads();
    int e0 = b * CHUNK, e1 = e0 + CHUNK;
    for (int e = e0 + t; e < e1; e += 256) {
        int d = ei[E_EDGES + e];
        atomicAdd(&hist[d >> 7], 1);
    }
    __syncthreads();
    for (int k = t; k < NBUCK; k += 256) histPB[k * PB + b] = hist[k];
}

// ---------------- per-bucket row scan (one block per bucket) ----------------
__global__ __launch_bounds__(256) void scan_rows(int* __restrict__ histPB,
                                                 int* __restrict__ bucket_tot) {
    __shared__ int wsum[4];
    int k = blockIdx.x, t = threadIdx.x, lane = t & 63, wv = t >> 6;
    int v = (t < PB) ? histPB[k * PB + t] : 0;
    int s = v;
#pragma unroll
    for (int off = 1; off < 64; off <<= 1) {
        int u = __shfl_up(s, off, 64);
        if (lane >= off) s += u;
    }
    if (lane == 63) wsum[wv] = s;
    __syncthreads();
    int wbase = 0;
    for (int w = 0; w < wv; w++) wbase += wsum[w];
    if (t < PB) histPB[k * PB + t] = wbase + s - v;
    if (t == 255) bucket_tot[k] = wbase + s;
}

// ---------------- scan bucket totals -> bucket_base (782, 4/thread) --------
__global__ __launch_bounds__(256) void scan_totals(const int* __restrict__ bucket_tot,
                                                   int* __restrict__ bucket_base) {
    __shared__ int wsum[4];
    int t = threadIdx.x, lane = t & 63, wv = t >> 6;
    int a[4];
    int s = 0;
#pragma unroll
    for (int q = 0; q < 4; q++) {
        int idx = t * 4 + q;
        a[q] = (idx < NBUCK) ? bucket_tot[idx] : 0;
        s += a[q];
    }
    int sc = s;
#pragma unroll
    for (int off = 1; off < 64; off <<= 1) {
        int u = __shfl_up(sc, off, 64);
        if (lane >= off) sc += u;
    }
    if (lane == 63) wsum[wv] = sc;
    __syncthreads();
    int wbase = 0;
    for (int w = 0; w < wv; w++) wbase += wsum[w];
    int run = wbase + sc - s;
#pragma unroll
    for (int q = 0; q < 4; q++) {
        int idx = t * 4 + q;
        if (idx < NBUCK) bucket_base[idx] = run;
        run += a[q];
    }
    if (t == 255) bucket_base[NBUCK] = run;   // = E
}

// ---------------- pass A2: bucket-scatter packed edges ----------------
__global__ __launch_bounds__(256) void passA2_scatter(const int* __restrict__ ei,
                                                      const int* __restrict__ histPB,
                                                      const int* __restrict__ bucket_base,
                                                      int* __restrict__ ebuf) {
    __shared__ int cur[NBUCK];
    int t = threadIdx.x, b = blockIdx.x;
    for (int k = t; k < NBUCK; k += 256) cur[k] = bucket_base[k] + histPB[k * PB + b];
    __syncthreads();
    int e0 = b * CHUNK, e1 = e0 + CHUNK;
    for (int e = e0 + t; e < e1; e += 256) {
        int s = ei[e];
        int d = ei[E_EDGES + e];
        int bk = d >> 7;
        int pos = atomicAdd(&cur[bk], 1);
        ebuf[pos] = s | ((d & 127) << 17);
    }
}

// ---- pass B: per-bucket place, (chunk, node)-sorted; emits cp + dinv ----
// csr_pk keeps the full pack (src | nd<<17).
__global__ __launch_bounds__(256) void passB_place(const int* __restrict__ ebuf,
                                                   const int* __restrict__ bucket_base,
                                                   int* __restrict__ csr_pk,
                                                   float* __restrict__ dinv,
                                                   int* __restrict__ cp) {
    __shared__ int hist[CCH * BN_];   // c-major: hist[c*128 + nd]
    __shared__ int wsum[4];
    int b = blockIdx.x, t = threadIdx.x, lane = t & 63, wv = t >> 6;
    int base = bucket_base[b], end = bucket_base[b + 1];
    for (int k = t; k < CCH * BN_; k += 256) hist[k] = 0;
    __syncthreads();
    for (int k = base + t; k < end; k += 256) {
        int pv = ebuf[k];
        int nd = (pv >> 17) & 127;
        int c = (pv & 0x1FFFF) / CNODES;
        atomicAdd(&hist[c * BN_ + nd], 1);
    }
    __syncthreads();
    // per-node degree -> dinv
    if (t < BN_) {
        int tot = 0;
#pragma unroll
        for (int c = 0; c < CCH; c++) tot += hist[c * BN_ + t];
        int node = b * BN_ + t;
        if (node < N_NODES) dinv[node] = rsqrtf((float)tot + 1.0f);
    }
    // block exclusive scan of hist[0..767], 3 per thread (768 = 256*3)
    int i0 = t * 3;
    int a0 = hist[i0], a1 = hist[i0 + 1], a2 = hist[i0 + 2];
    int s = a0 + a1 + a2;
    int sc = s;
#pragma unroll
    for (int off = 1; off < 64; off <<= 1) {
        int u = __shfl_up(sc, off, 64);
        if (lane >= off) sc += u;
    }
    if (lane == 63) wsum[wv] = sc;
    __syncthreads();   // reads of hist done + wsum visible
    int wbase = 0;
    for (int w = 0; w < wv; w++) wbase += wsum[w];
    int e0 = wbase + sc - s;
    int e1 = e0 + a0, e2 = e1 + a1;
    hist[i0] = e0; hist[i0 + 1] = e1; hist[i0 + 2] = e2;
    // cp[c][node] = base + scanned  (idx = c*128+nd)
    {
        int c0 = i0 >> 7, n0 = i0 & 127;
        cp[c0 * CPS + b * BN_ + n0] = base + e0;
        int c1 = (i0 + 1) >> 7, n1 = (i0 + 1) & 127;
        cp[c1 * CPS + b * BN_ + n1] = base + e1;
        int c2 = (i0 + 2) >> 7, n2 = (i0 + 2) & 127;
        cp[c2 * CPS + b * BN_ + n2] = base + e2;
    }
    __syncthreads();
    // placement
    for (int k = base + t; k < end; k += 256) {
        int pv = ebuf[k];
        int nd = (pv >> 17) & 127;
        int c = (pv & 0x1FFFF) / CNODES;
        int pos = atomicAdd(&hist[c * BN_ + nd], 1);
        csr_pk[base + pos] = pv;
    }
}

// ---------------- MFMA GEMM: hs(bf16) = (X @ W) * dinv[row] ----------------
template<int K, bool BF16IN>
__global__ __launch_bounds__(256) void gemm_bf16(const void* __restrict__ Xv,
                                                 const float* __restrict__ W,   // [K][64]
                                                 const float* __restrict__ dinv,
                                                 ushort* __restrict__ hs) {     // [N][64] bf16
    constexpr int KP = K + 8;
    __shared__ ushort A_lds[64][KP];
    __shared__ ushort Wt_lds[64][KP];
    int t = threadIdx.x;
    long row0 = (long)blockIdx.x * 64;

    for (int i = t; i < K * 16; i += 256) {
        float4 w4 = ((const float4*)W)[i];
        int k = i >> 4, n = (i & 15) * 4;
        Wt_lds[n + 0][k] = f2bf(w4.x);
        Wt_lds[n + 1][k] = f2bf(w4.y);
        Wt_lds[n + 2][k] = f2bf(w4.z);
        Wt_lds[n + 3][k] = f2bf(w4.w);
    }
    if (BF16IN) {
        constexpr int K2 = K / 2;
        const unsigned* X = (const unsigned*)Xv;
        for (int i = t; i < 64 * K2; i += 256) {
            int r = i / K2, c = i % K2;
            unsigned val = 0;
            long row = row0 + r;
            if (row < N_NODES) val = X[row * K2 + c];
            *(unsigned*)&A_lds[r][c * 2] = val;
        }
    } else {
        constexpr int K4 = K / 4;
        const float* X = (const float*)Xv;
        for (int i = t; i < 64 * K4; i += 256) {
            int r = i / K4, c = i % K4;
            float4 val = make_float4(0.f, 0.f, 0.f, 0.f);
            long row = row0 + r;
            if (row < N_NODES) val = ((const float4*)X)[row * K4 + c];
            int cb = c * 4;
            A_lds[r][cb + 0] = f2bf(val.x);
            A_lds[r][cb + 1] = f2bf(val.y);
            A_lds[r][cb + 2] = f2bf(val.z);
            A_lds[r][cb + 3] = f2bf(val.w);
        }
    }
    __syncthreads();

    int w = t >> 6, l = t & 63;
    int m = l & 15, quad = l >> 4;
    f32x4 acc[4];
#pragma unroll
    for (int c = 0; c < 4; c++) acc[c] = (f32x4){0.f, 0.f, 0.f, 0.f};

#pragma unroll
    for (int ch = 0; ch < K / 32; ch++) {
        short8 a = *(const short8*)&A_lds[16 * w + m][32 * ch + 8 * quad];
#pragma unroll
        for (int c = 0; c < 4; c++) {
            short8 b = *(const short8*)&Wt_lds[16 * c + m][32 * ch + 8 * quad];
            acc[c] = __builtin_amdgcn_mfma_f32_16x16x32_bf16(a, b, acc[c], 0, 0, 0);
        }
    }

#pragma unroll
    for (int r = 0; r < 4; r++) {
        long node = row0 + 16 * w + quad * 4 + r;
        if (node < N_NODES) {
            float dv = dinv[node];
#pragma unroll
            for (int c = 0; c < 4; c++)
                hs[node * 64 + 16 * c + m] = f2bf(acc[c][r] * dv);
        }
    }
}

// ------- edge-parallel chunk-sweep gather with LDS accumulators -------
// One block per bucket (128 dst nodes). acc[128][64] f32 in LDS (32 KB ->
// 5 blocks/CU; all 782 blocks co-resident -> chunk phases stay coherent).
// Per chunk: 4 waves stream the contiguous (bucket,chunk) edge run, 8
// independent edges in flight each; lane = feature; ds_add_f32 accumulate.
template<bool LAST>
__global__ __launch_bounds__(256) void gather_block(const int* __restrict__ csr_pk,
                                                    const int* __restrict__ cp,
                                                    const int* __restrict__ bucket_base,
                                                    const ushort* __restrict__ hs,
                                                    const float* __restrict__ dinv,
                                                    const float* __restrict__ b,
                                                    const float* __restrict__ g,
                                                    const float* __restrict__ beta,
                                                    const float* __restrict__ m,
                                                    const float* __restrict__ v,
                                                    ushort* __restrict__ y,
                                                    const float* __restrict__ W3,
                                                    float* __restrict__ hs3) {
    __shared__ float acc[BN_ * 64];
    int bkt = blockIdx.x, t = threadIdx.x;
    int wv = t >> 6, j = t & 63;
    int nfirst = bkt * BN_;

    for (int k = t; k < BN_ * 64; k += 256) acc[k] = 0.f;
    __syncthreads();

    for (int c = 0; c < CCH; c++) {
        int eb = cp[c * CPS + nfirst];
        int ee = (c == CCH - 1) ? bucket_base[bkt + 1] : cp[(c + 1) * CPS + nfirst];
        int e = eb + wv;
        while (e + 28 < ee) {
            int pv[8];
#pragma unroll
            for (int q = 0; q < 8; q++) pv[q] = csr_pk[e + 4 * q];
            float f[8];
#pragma unroll
            for (int q = 0; q < 8; q++)
                f[q] = bf2f(hs[(long)(pv[q] & 0x1FFFF) * 64 + j]);
#pragma unroll
            for (int q = 0; q < 8; q++)
                atomicAdd(&acc[((pv[q] >> 17) & 127) * 64 + j], f[q]);
            e += 32;
        }
        for (; e < ee; e += 4) {
            int pv = csr_pk[e];
            float f = bf2f(hs[(long)(pv & 0x1FFFF) * 64 + j]);
            atomicAdd(&acc[((pv >> 17) & 127) * 64 + j], f);
        }
    }
    __syncthreads();

    // epilogue: 32 nodes per wave
    float bj = b[j], mj = m[j], bej = beta[j];
    float scj = g[j] * rsqrtf(v[j] + BN_EPS_);
    float w3 = LAST ? W3[j] : 0.f;
    for (int nb = 0; nb < 32; nb++) {
        int ln = wv * 32 + nb;
        int i = nfirst + ln;
        if (i >= N_NODES) break;
        float a = acc[ln * 64 + j] + bf2f(hs[(long)i * 64 + j]);   // + self-loop
        float di = dinv[i];
        float o = fmaxf((di * a + bj - mj) * scj + bej, 0.f);
        if (LAST) {
            float p = o * w3;
#pragma unroll
            for (int off = 32; off > 0; off >>= 1) p += __shfl_xor(p, off, 64);
            if (j == 0) hs3[i] = p * di;
        } else {
            y[(long)i * 64 + j] = f2bf(o);
        }
    }
}

// ---------------- layer-3 pull + sigmoid (6 segments per node) -------------
__global__ __launch_bounds__(256) void gather3(const int* __restrict__ cp,
                                               const int* __restrict__ bucket_base,
                                               const int* __restrict__ csr_pk,
                                               const float* __restrict__ hs3,
                                               const float* __restrict__ dinv,
                                               const float* __restrict__ b3,
                                               float* __restrict__ out, int n) {
    int i = blockIdx.x * 256 + threadIdx.x;
    if (i >= n) return;
    int bkt = i >> 7;
    int nfirst = bkt << 7;
    float s0 = hs3[i], s1 = 0.f, s2 = 0.f, s3 = 0.f;
    for (int c = 0; c < CCH; c++) {
        int ks = cp[c * CPS + i];
        int ke;
        if ((i & 127) != 127) ke = cp[c * CPS + i + 1];
        else ke = (c == CCH - 1) ? bucket_base[bkt + 1] : cp[(c + 1) * CPS + nfirst];
        int k = ks;
        for (; k + 3 < ke; k += 4) {
            s0 += hs3[csr_pk[k] & 0x1FFFF];
            s1 += hs3[csr_pk[k + 1] & 0x1FFFF];
            s2 += hs3[csr_pk[k + 2] & 0x1FFFF];
            s3 += hs3[csr_pk[k + 3] & 0x1FFFF];
        }
        for (; k < ke; k++) s0 += hs3[csr_pk[k] & 0x1FFFF];
    }
    float z = dinv[i] * ((s0 + s1) + (s2 + s3)) + b3[0];
    out[i] = 1.f / (1.f + expf(-z));
}

extern "C" void kernel_launch(void* const* d_in, const int* in_sizes, int n_in,
                              void* d_out, int out_size, void* d_ws, size_t ws_size,
                              hipStream_t stream) {
    const int N = N_NODES;
    const int E = E_EDGES;

    const float* x   = (const float*)d_in[0];
    const int*   ei  = (const int*)d_in[1];   // [2, E]: row0=src, row1=dst
    const float* W1  = (const float*)d_in[2];
    const float* b1  = (const float*)d_in[3];
    const float* W2  = (const float*)d_in[4];
    const float* b2  = (const float*)d_in[5];
    const float* W3  = (const float*)d_in[6];
    const float* b3  = (const float*)d_in[7];
    const float* g1  = (const float*)d_in[8];
    const float* bt1 = (const float*)d_in[9];
    const float* m1  = (const float*)d_in[10];
    const float* v1  = (const float*)d_in[11];
    const float* g2  = (const float*)d_in[12];
    const float* bt2 = (const float*)d_in[13];
    const float* m2  = (const float*)d_in[14];
    const float* v2  = (const float*)d_in[15];
    float* out = (float*)d_out;

    // workspace layout (4-byte units)
    int*    wsi         = (int*)d_ws;
    float*  dinv        = (float*)wsi;                    // N
    float*  hs3         = (float*)(wsi + (long)N);        // N
    int*    cp          = wsi + 2L * N;                   // CCH*CPS
    int*    histPB      = cp + (long)CCH * CPS;           // NBUCK*PB
    int*    bucket_tot  = histPB + (long)NBUCK * PB;      // NBUCK (pad 800)
    int*    bucket_base = bucket_tot + 800;               // NBUCK+1 (pad 800)
    int*    csr_pk      = bucket_base + 800;              // E (packed src|nd<<17)
    ushort* hsb         = (ushort*)(csr_pk + (long)E);    // N*64 bf16 = 32N ints
    ushort* yb          = (ushort*)(csr_pk + (long)E + 32L * N); // N*64 bf16
    int*    ebuf        = (int*)hsb;                      // E ints, aliases hsb

    // ---- CSR build: bucketed counting sort, (chunk, node) order ----
    passA1_hist<<<PB, 256, 0, stream>>>(ei, histPB);
    scan_rows<<<NBUCK, 256, 0, stream>>>(histPB, bucket_tot);
    scan_totals<<<1, 256, 0, stream>>>(bucket_tot, bucket_base);
    passA2_scatter<<<PB, 256, 0, stream>>>(ei, histPB, bucket_base, ebuf);
    passB_place<<<NBUCK, 256, 0, stream>>>(ebuf, bucket_base, csr_pk, dinv, cp);

    // ---- layer 1 ----
    gemm_bf16<IN_DIM_, false><<<(N + 63) / 64, 256, 0, stream>>>(x, W1, dinv, hsb);
    gather_block<false><<<NBUCK, 256, 0, stream>>>(csr_pk, cp, bucket_base, hsb, dinv,
                                                   b1, g1, bt1, m1, v1, yb, W3, hs3);
    // ---- layer 2 (+ fused gemv3) ----
    gemm_bf16<HID_, true><<<(N + 63) / 64, 256, 0, stream>>>(yb, W2, dinv, hsb);
    gather_block<true><<<NBUCK, 256, 0, stream>>>(csr_pk, cp, bucket_base, hsb, dinv,
                                                  b2, g2, bt2, m2, v2, yb, W3, hs3);
    // ---- layer 3 ----
    gather3<<<(N + 255) / 256, 256, 0, stream>>>(cp, bucket_base, csr_pk, hs3, dinv,
                                                 b3, out, N);
}

// Round 9
// 438.615 us; speedup vs baseline: 6.6891x; 6.6891x over previous
//
#include <hip/hip_runtime.h>
#include <math.h>

#define N_NODES 100000
#define E_EDGES 3200000
#define IN_DIM_ 128
#define HID_ 64
#define BN_EPS_ 1e-5f

#define PB 200          // edge-chunk blocks
#define CHUNK 16000     // E / PB exactly
#define NBUCK 391       // ceil(N / 256): bucket = dst >> 8

#define CCH 6           // src chunks: row interiors sorted chunk-major
#define CNODES 16667    // ceil(N / CCH)

typedef __attribute__((ext_vector_type(8))) short short8;
typedef __attribute__((ext_vector_type(4))) float f32x4;

__device__ inline ushort f2bf(float f) {
    union { float f; unsigned u; } c; c.f = f;
    unsigned r = c.u + 0x7fff + ((c.u >> 16) & 1);   // RNE
    return (ushort)(r >> 16);
}
__device__ inline float bf_lo(unsigned p) { union { unsigned u; float f; } c; c.u = p << 16; return c.f; }
__device__ inline float bf_hi(unsigned p) { union { unsigned u; float f; } c; c.u = p & 0xffff0000u; return c.f; }

// ---------------- pass A1: per-block bucket histogram ----------------
__global__ __launch_bounds__(256) void passA1_hist(const int* __restrict__ ei,
                                                   int* __restrict__ histPB) {
    __shared__ int hist[NBUCK];
    int t = threadIdx.x, b = blockIdx.x;
    for (int k = t; k < NBUCK; k += 256) hist[k] = 0;
    __syncthreads();
    int e0 = b * CHUNK, e1 = e0 + CHUNK;
    for (int e = e0 + t; e < e1; e += 256) {
        int d = ei[E_EDGES + e];
        atomicAdd(&hist[d >> 8], 1);
    }
    __syncthreads();
    for (int k = t; k < NBUCK; k += 256) histPB[k * PB + b] = hist[k];
}

// ---------------- per-bucket row scan ----------------
__global__ __launch_bounds__(256) void scan_rows(int* __restrict__ histPB,
                                                 int* __restrict__ bucket_tot) {
    __shared__ int wsum[4];
    int k = blockIdx.x, t = threadIdx.x, lane = t & 63, wv = t >> 6;
    int v = (t < PB) ? histPB[k * PB + t] : 0;
    int s = v;
#pragma unroll
    for (int off = 1; off < 64; off <<= 1) {
        int u = __shfl_up(s, off, 64);
        if (lane >= off) s += u;
    }
    if (lane == 63) wsum[wv] = s;
    __syncthreads();
    int wbase = 0;
    for (int w = 0; w < wv; w++) wbase += wsum[w];
    if (t < PB) histPB[k * PB + t] = wbase + s - v;
    if (t == 255) bucket_tot[k] = wbase + s;
}

// ---------------- scan bucket totals -> bucket_base ----------------
__global__ __launch_bounds__(512) void scan_totals(const int* __restrict__ bucket_tot,
                                                   int* __restrict__ bucket_base,
                                                   int* __restrict__ row_ptr) {
    __shared__ int wsum[8];
    int t = threadIdx.x, lane = t & 63, wv = t >> 6;
    int v = (t < NBUCK) ? bucket_tot[t] : 0;
    int s = v;
#pragma unroll
    for (int off = 1; off < 64; off <<= 1) {
        int u = __shfl_up(s, off, 64);
        if (lane >= off) s += u;
    }
    if (lane == 63) wsum[wv] = s;
    __syncthreads();
    int wbase = 0;
    for (int w = 0; w < wv; w++) wbase += wsum[w];
    if (t < NBUCK) bucket_base[t] = wbase + s - v;
    if (t == 0) {
        bucket_base[NBUCK] = E_EDGES;
        row_ptr[N_NODES] = E_EDGES;
    }
}

// ---------------- pass A2: bucket-scatter packed edges ----------------
__global__ __launch_bounds__(256) void passA2_scatter(const int* __restrict__ ei,
                                                      const int* __restrict__ histPB,
                                                      const int* __restrict__ bucket_base,
                                                      int* __restrict__ ebuf) {
    __shared__ int cur[NBUCK];
    int t = threadIdx.x, b = blockIdx.x;
    for (int k = t; k < NBUCK; k += 256) cur[k] = bucket_base[k] + histPB[k * PB + b];
    __syncthreads();
    int e0 = b * CHUNK, e1 = e0 + CHUNK;
    for (int e = e0 + t; e < e1; e += 256) {
        int s = ei[e];
        int d = ei[E_EDGES + e];
        int bk = d >> 8;
        int pos = atomicAdd(&cur[bk], 1);
        ebuf[pos] = s | ((d & 255) << 17);
    }
}

// ---- pass B: per-bucket place; row interiors chunk-major; row_ptr + dinv ----
__global__ __launch_bounds__(256) void passB_place(const int* __restrict__ ebuf,
                                                   const int* __restrict__ bucket_base,
                                                   int* __restrict__ row_ptr,
                                                   int* __restrict__ csr_src,
                                                   float* __restrict__ dinv) {
    __shared__ int hist[256 * CCH];   // nd-major: hist[nd*CCH + c]
    __shared__ int wsum[4];
    int b = blockIdx.x, t = threadIdx.x, lane = t & 63, wv = t >> 6;
    int base = bucket_base[b], end = bucket_base[b + 1];
    for (int k = t; k < 256 * CCH; k += 256) hist[k] = 0;
    __syncthreads();
    for (int k = base + t; k < end; k += 256) {
        int pv = ebuf[k];
        int nd = (pv >> 17) & 255;
        int c = (pv & 0x1FFFF) / CNODES;
        atomicAdd(&hist[nd * CCH + c], 1);
    }
    __syncthreads();
    int v[CCH];
    int tot = 0;
#pragma unroll
    for (int c = 0; c < CCH; c++) { v[c] = hist[t * CCH + c]; tot += v[c]; }
    int s = tot;
#pragma unroll
    for (int off = 1; off < 64; off <<= 1) {
        int u = __shfl_up(s, off, 64);
        if (lane >= off) s += u;
    }
    if (lane == 63) wsum[wv] = s;
    __syncthreads();
    int wbase = 0;
    for (int w = 0; w < wv; w++) wbase += wsum[w];
    int excl = wbase + s - tot;          // node's exclusive start within bucket
    int node = b * 256 + t;
    if (node < N_NODES) {
        row_ptr[node] = base + excl;
        dinv[node] = rsqrtf((float)tot + 1.0f);
    }
    int run = excl;
#pragma unroll
    for (int c = 0; c < CCH; c++) {      // per-(node,chunk) cursors
        hist[t * CCH + c] = run;
        run += v[c];
    }
    __syncthreads();
    for (int k = base + t; k < end; k += 256) {
        int pv = ebuf[k];
        int nd = (pv >> 17) & 255;
        int c = (pv & 0x1FFFF) / CNODES;
        int pos = atomicAdd(&hist[nd * CCH + c], 1);
        csr_src[base + pos] = pv & 0x1FFFF;
    }
}

// ---------------- MFMA GEMM: hs(bf16) = (X @ W) * dinv[row] ----------------
template<int K, bool BF16IN>
__global__ __launch_bounds__(256) void gemm_bf16(const void* __restrict__ Xv,
                                                 const float* __restrict__ W,   // [K][64]
                                                 const float* __restrict__ dinv,
                                                 ushort* __restrict__ hs) {     // [N][64] bf16
    constexpr int KP = K + 8;
    __shared__ ushort A_lds[64][KP];
    __shared__ ushort Wt_lds[64][KP];
    int t = threadIdx.x;
    long row0 = (long)blockIdx.x * 64;

    for (int i = t; i < K * 16; i += 256) {
        float4 w4 = ((const float4*)W)[i];
        int k = i >> 4, n = (i & 15) * 4;
        Wt_lds[n + 0][k] = f2bf(w4.x);
        Wt_lds[n + 1][k] = f2bf(w4.y);
        Wt_lds[n + 2][k] = f2bf(w4.z);
        Wt_lds[n + 3][k] = f2bf(w4.w);
    }
    if (BF16IN) {
        constexpr int K2 = K / 2;
        const unsigned* X = (const unsigned*)Xv;
        for (int i = t; i < 64 * K2; i += 256) {
            int r = i / K2, c = i % K2;
            unsigned val = 0;
            long row = row0 + r;
            if (row < N_NODES) val = X[row * K2 + c];
            *(unsigned*)&A_lds[r][c * 2] = val;
        }
    } else {
        constexpr int K4 = K / 4;
        const float* X = (const float*)Xv;
        for (int i = t; i < 64 * K4; i += 256) {
            int r = i / K4, c = i % K4;
            float4 val = make_float4(0.f, 0.f, 0.f, 0.f);
            long row = row0 + r;
            if (row < N_NODES) val = ((const float4*)X)[row * K4 + c];
            int cb = c * 4;
            A_lds[r][cb + 0] = f2bf(val.x);
            A_lds[r][cb + 1] = f2bf(val.y);
            A_lds[r][cb + 2] = f2bf(val.z);
            A_lds[r][cb + 3] = f2bf(val.w);
        }
    }
    __syncthreads();

    int w = t >> 6, l = t & 63;
    int m = l & 15, quad = l >> 4;
    f32x4 acc[4];
#pragma unroll
    for (int c = 0; c < 4; c++) acc[c] = (f32x4){0.f, 0.f, 0.f, 0.f};

#pragma unroll
    for (int ch = 0; ch < K / 32; ch++) {
        short8 a = *(const short8*)&A_lds[16 * w + m][32 * ch + 8 * quad];
#pragma unroll
        for (int c = 0; c < 4; c++) {
            short8 b = *(const short8*)&Wt_lds[16 * c + m][32 * ch + 8 * quad];
            acc[c] = __builtin_amdgcn_mfma_f32_16x16x32_bf16(a, b, acc[c], 0, 0, 0);
        }
    }

#pragma unroll
    for (int r = 0; r < 4; r++) {
        long node = row0 + 16 * w + quad * 4 + r;
        if (node < N_NODES) {
            float dv = dinv[node];
#pragma unroll
            for (int c = 0; c < 4; c++)
                hs[node * 64 + 16 * c + m] = f2bf(acc[c][r] * dv);
        }
    }
}

// ---------------- pull-gather (bf16 hs) + fused BN/ReLU ----------------
// One wave per node. half = lane>>5 picks edge parity, u = lane&31 picks the
// uint (2 bf16 features). 8 edges in flight per half = 16 per wave.
// LAST=false: write y (bf16 packed). LAST=true: fuse gemv3 -> hs3[i].
template<bool LAST>
__global__ __launch_bounds__(256) void gather_feat(const int* __restrict__ row_ptr,
                                                   const int* __restrict__ csr_src,
                                                   const ushort* __restrict__ hs,
                                                   const float* __restrict__ dinv,
                                                   const float* __restrict__ b,
                                                   const float* __restrict__ g,
                                                   const float* __restrict__ beta,
                                                   const float* __restrict__ m,
                                                   const float* __restrict__ v,
                                                   unsigned* __restrict__ y,
                                                   const float* __restrict__ W3,
                                                   float* __restrict__ hs3, int n) {
    int i = (blockIdx.x * 256 + threadIdx.x) >> 6;
    if (i >= n) return;
    int l = threadIdx.x & 63;
    int half = l >> 5, u = l & 31;
    const unsigned* H = (const unsigned*)hs;
    int beg = row_ptr[i], end = row_ptr[i + 1];
    float a0 = 0.f, a1 = 0.f;
    int k = beg + half;
    for (; k + 14 < end; k += 16) {
        int s0 = csr_src[k],      s1 = csr_src[k + 2],  s2 = csr_src[k + 4],  s3 = csr_src[k + 6];
        int s4 = csr_src[k + 8],  s5 = csr_src[k + 10], s6 = csr_src[k + 12], s7 = csr_src[k + 14];
        unsigned p0 = H[s0 * 32 + u], p1 = H[s1 * 32 + u];
        unsigned p2 = H[s2 * 32 + u], p3 = H[s3 * 32 + u];
        unsigned p4 = H[s4 * 32 + u], p5 = H[s5 * 32 + u];
        unsigned p6 = H[s6 * 32 + u], p7 = H[s7 * 32 + u];
        a0 += ((bf_lo(p0) + bf_lo(p1)) + (bf_lo(p2) + bf_lo(p3))) +
              ((bf_lo(p4) + bf_lo(p5)) + (bf_lo(p6) + bf_lo(p7)));
        a1 += ((bf_hi(p0) + bf_hi(p1)) + (bf_hi(p2) + bf_hi(p3))) +
              ((bf_hi(p4) + bf_hi(p5)) + (bf_hi(p6) + bf_hi(p7)));
    }
    for (; k < end; k += 2) {
        unsigned p = H[csr_src[k] * 32 + u];
        a0 += bf_lo(p);
        a1 += bf_hi(p);
    }
    a0 += __shfl_xor(a0, 32, 64);
    a1 += __shfl_xor(a1, 32, 64);
    // self-loop term
    unsigned ps = H[(long)i * 32 + u];
    a0 += bf_lo(ps);
    a1 += bf_hi(ps);

    float2 bb = ((const float2*)b)[u];
    float2 gg = ((const float2*)g)[u];
    float2 be = ((const float2*)beta)[u];
    float2 mm = ((const float2*)m)[u];
    float2 vv = ((const float2*)v)[u];
    float di = dinv[i];
    float s0 = gg.x * rsqrtf(vv.x + BN_EPS_);
    float s1 = gg.y * rsqrtf(vv.y + BN_EPS_);
    float o0 = fmaxf((di * a0 + bb.x - mm.x) * s0 + be.x, 0.f);
    float o1 = fmaxf((di * a1 + bb.y - mm.y) * s1 + be.y, 0.f);

    if (LAST) {
        // each 32-lane half holds the full 64-feature vector -> dot with W3
        float2 w3 = ((const float2*)W3)[u];
        float p = o0 * w3.x + o1 * w3.y;
#pragma unroll
        for (int off = 16; off > 0; off >>= 1)
            p += __shfl_down(p, off, 32);
        if (l == 0) hs3[i] = p * di;
    } else {
        if (half == 0)
            y[(long)i * 32 + u] = (unsigned)f2bf(o0) | ((unsigned)f2bf(o1) << 16);
    }
}

// ---------------- layer-3 pull + sigmoid (8 loads in flight) ----------------
__global__ __launch_bounds__(256) void gather3(const int* __restrict__ row_ptr,
                                               const int* __restrict__ csr_src,
                                               const float* __restrict__ hs3,
                                               const float* __restrict__ dinv,
                                               const float* __restrict__ b3,
                                               float* __restrict__ out, int n) {
    int i = blockIdx.x * 256 + threadIdx.x;
    if (i >= n) return;
    int beg = row_ptr[i], end = row_ptr[i + 1];
    float s0 = hs3[i], s1 = 0.f, s2 = 0.f, s3 = 0.f;
    float s4 = 0.f, s5 = 0.f, s6 = 0.f, s7 = 0.f;
    int k = beg;
    for (; k + 8 <= end; k += 8) {
        s0 += hs3[csr_src[k]];
        s1 += hs3[csr_src[k + 1]];
        s2 += hs3[csr_src[k + 2]];
        s3 += hs3[csr_src[k + 3]];
        s4 += hs3[csr_src[k + 4]];
        s5 += hs3[csr_src[k + 5]];
        s6 += hs3[csr_src[k + 6]];
        s7 += hs3[csr_src[k + 7]];
    }
    for (; k < end; k++) s0 += hs3[csr_src[k]];
    float z = dinv[i] * (((s0 + s1) + (s2 + s3)) + ((s4 + s5) + (s6 + s7))) + b3[0];
    out[i] = 1.f / (1.f + expf(-z));
}

extern "C" void kernel_launch(void* const* d_in, const int* in_sizes, int n_in,
                              void* d_out, int out_size, void* d_ws, size_t ws_size,
                              hipStream_t stream) {
    const int N = N_NODES;
    const int E = E_EDGES;

    const float* x   = (const float*)d_in[0];
    const int*   ei  = (const int*)d_in[1];   // [2, E]: row0=src, row1=dst
    const float* W1  = (const float*)d_in[2];
    const float* b1  = (const float*)d_in[3];
    const float* W2  = (const float*)d_in[4];
    const float* b2  = (const float*)d_in[5];
    const float* W3  = (const float*)d_in[6];
    const float* b3  = (const float*)d_in[7];
    const float* g1  = (const float*)d_in[8];
    const float* bt1 = (const float*)d_in[9];
    const float* m1  = (const float*)d_in[10];
    const float* v1  = (const float*)d_in[11];
    const float* g2  = (const float*)d_in[12];
    const float* bt2 = (const float*)d_in[13];
    const float* m2  = (const float*)d_in[14];
    const float* v2  = (const float*)d_in[15];
    float* out = (float*)d_out;

    // workspace layout (4-byte units)
    int*    wsi         = (int*)d_ws;
    float*  dinv        = (float*)wsi;                    // N
    float*  hs3         = (float*)(wsi + (long)N);        // N
    int*    row_ptr     = wsi + 2L * N;                   // N+1 (pad 16)
    int*    histPB      = wsi + 3L * N + 16;              // NBUCK*PB = 78200
    int*    bucket_tot  = histPB + NBUCK * PB;            // NBUCK (pad 400)
    int*    bucket_base = bucket_tot + 400;               // NBUCK+1 (pad 400)
    int*    csr_src     = bucket_base + 400;              // E
    ushort* hsb         = (ushort*)(csr_src + (long)E);   // N*64 bf16 = 32N ints
    unsigned* yb        = (unsigned*)(csr_src + (long)E + 32L * N); // N*32 uints
    int*    ebuf        = (int*)hsb;                      // E ints, aliases hsb

    // ---- CSR build (bucketed counting sort; rows chunk-major inside) ----
    passA1_hist<<<PB, 256, 0, stream>>>(ei, histPB);
    scan_rows<<<NBUCK, 256, 0, stream>>>(histPB, bucket_tot);
    scan_totals<<<1, 512, 0, stream>>>(bucket_tot, bucket_base, row_ptr);
    passA2_scatter<<<PB, 256, 0, stream>>>(ei, histPB, bucket_base, ebuf);
    passB_place<<<NBUCK, 256, 0, stream>>>(ebuf, bucket_base, row_ptr, csr_src, dinv);

    // ---- layer 1 ----
    gemm_bf16<IN_DIM_, false><<<(N + 63) / 64, 256, 0, stream>>>(x, W1, dinv, hsb);
    gather_feat<false><<<N / 4, 256, 0, stream>>>(row_ptr, csr_src, hsb, dinv,
                                                  b1, g1, bt1, m1, v1, yb, W3, hs3, N);
    // ---- layer 2 (+ fused gemv3) ----
    gemm_bf16<HID_, true><<<(N + 63) / 64, 256, 0, stream>>>(yb, W2, dinv, hsb);
    gather_feat<true><<<N / 4, 256, 0, stream>>>(row_ptr, csr_src, hsb, dinv,
                                                 b2, g2, bt2, m2, v2, yb, W3, hs3, N);
    // ---- layer 3 ----
    gather3<<<(N + 255) / 256, 256, 0, stream>>>(row_ptr, csr_src, hs3, dinv, b3, out, N);
}

// Round 10
// 432.081 us; speedup vs baseline: 6.7902x; 1.0151x over previous
//
#include <hip/hip_runtime.h>
#include <math.h>

#define N_NODES 100000
#define E_EDGES 3200000
#define IN_DIM_ 128
#define HID_ 64
#define BN_EPS_ 1e-5f

#define PB 200          // edge-chunk blocks
#define CHUNK 16000     // E / PB exactly
#define NBUCK 391       // ceil(N / 256): bucket = dst >> 8

typedef __attribute__((ext_vector_type(8))) short short8;
typedef __attribute__((ext_vector_type(4))) float f32x4;

__device__ inline ushort f2bf(float f) {
    union { float f; unsigned u; } c; c.f = f;
    unsigned r = c.u + 0x7fff + ((c.u >> 16) & 1);   // RNE
    return (ushort)(r >> 16);
}
__device__ inline float bf_lo(unsigned p) { union { unsigned u; float f; } c; c.u = p << 16; return c.f; }
__device__ inline float bf_hi(unsigned p) { union { unsigned u; float f; } c; c.u = p & 0xffff0000u; return c.f; }

// ---------------- pass A1: per-block bucket histogram ----------------
__global__ __launch_bounds__(256) void passA1_hist(const int* __restrict__ ei,
                                                   int* __restrict__ histPB) {
    __shared__ int hist[NBUCK];
    int t = threadIdx.x, b = blockIdx.x;
    for (int k = t; k < NBUCK; k += 256) hist[k] = 0;
    __syncthreads();
    int e0 = b * CHUNK, e1 = e0 + CHUNK;
    for (int e = e0 + t; e < e1; e += 256) {
        int d = ei[E_EDGES + e];
        atomicAdd(&hist[d >> 8], 1);
    }
    __syncthreads();
    for (int k = t; k < NBUCK; k += 256) histPB[k * PB + b] = hist[k];
}

// ---------------- per-bucket row scan ----------------
__global__ __launch_bounds__(256) void scan_rows(int* __restrict__ histPB,
                                                 int* __restrict__ bucket_tot) {
    __shared__ int wsum[4];
    int k = blockIdx.x, t = threadIdx.x, lane = t & 63, wv = t >> 6;
    int v = (t < PB) ? histPB[k * PB + t] : 0;
    int s = v;
#pragma unroll
    for (int off = 1; off < 64; off <<= 1) {
        int u = __shfl_up(s, off, 64);
        if (lane >= off) s += u;
    }
    if (lane == 63) wsum[wv] = s;
    __syncthreads();
    int wbase = 0;
    for (int w = 0; w < wv; w++) wbase += wsum[w];
    if (t < PB) histPB[k * PB + t] = wbase + s - v;
    if (t == 255) bucket_tot[k] = wbase + s;
}

// ---------------- scan bucket totals -> bucket_base ----------------
__global__ __launch_bounds__(512) void scan_totals(const int* __restrict__ bucket_tot,
                                                   int* __restrict__ bucket_base,
                                                   int* __restrict__ row_ptr) {
    __shared__ int wsum[8];
    int t = threadIdx.x, lane = t & 63, wv = t >> 6;
    int v = (t < NBUCK) ? bucket_tot[t] : 0;
    int s = v;
#pragma unroll
    for (int off = 1; off < 64; off <<= 1) {
        int u = __shfl_up(s, off, 64);
        if (lane >= off) s += u;
    }
    if (lane == 63) wsum[wv] = s;
    __syncthreads();
    int wbase = 0;
    for (int w = 0; w < wv; w++) wbase += wsum[w];
    if (t < NBUCK) bucket_base[t] = wbase + s - v;
    if (t == 0) {
        bucket_base[NBUCK] = E_EDGES;
        row_ptr[N_NODES] = E_EDGES;
    }
}

// ---------------- pass A2: bucket-scatter packed edges ----------------
__global__ __launch_bounds__(256) void passA2_scatter(const int* __restrict__ ei,
                                                      const int* __restrict__ histPB,
                                                      const int* __restrict__ bucket_base,
                                                      int* __restrict__ ebuf) {
    __shared__ int cur[NBUCK];
    int t = threadIdx.x, b = blockIdx.x;
    for (int k = t; k < NBUCK; k += 256) cur[k] = bucket_base[k] + histPB[k * PB + b];
    __syncthreads();
    int e0 = b * CHUNK, e1 = e0 + CHUNK;
    for (int e = e0 + t; e < e1; e += 256) {
        int s = ei[e];
        int d = ei[E_EDGES + e];
        int bk = d >> 8;
        int pos = atomicAdd(&cur[bk], 1);
        ebuf[pos] = s | ((d & 255) << 17);
    }
}

// ---------------- pass B: per-bucket place + row_ptr + dinv (simple) -------
__global__ __launch_bounds__(256) void passB_place(const int* __restrict__ ebuf,
                                                   const int* __restrict__ bucket_base,
                                                   int* __restrict__ row_ptr,
                                                   int* __restrict__ csr_src,
                                                   float* __restrict__ dinv) {
    __shared__ int hist[256];
    __shared__ int wsum[4];
    int b = blockIdx.x, t = threadIdx.x, lane = t & 63, wv = t >> 6;
    int base = bucket_base[b], end = bucket_base[b + 1];
    hist[t] = 0;
    __syncthreads();
    for (int k = base + t; k < end; k += 256)
        atomicAdd(&hist[ebuf[k] >> 17], 1);
    __syncthreads();
    int v = hist[t];
    int s = v;
#pragma unroll
    for (int off = 1; off < 64; off <<= 1) {
        int u = __shfl_up(s, off, 64);
        if (lane >= off) s += u;
    }
    if (lane == 63) wsum[wv] = s;
    __syncthreads();
    int wbase = 0;
    for (int w = 0; w < wv; w++) wbase += wsum[w];
    int excl = wbase + s - v;
    int node = b * 256 + t;
    if (node < N_NODES) {
        row_ptr[node] = base + excl;
        dinv[node] = rsqrtf((float)v + 1.0f);
    }
    __syncthreads();
    hist[t] = excl;  // reuse as cursor
    __syncthreads();
    for (int k = base + t; k < end; k += 256) {
        int pv = ebuf[k];
        int pos = atomicAdd(&hist[pv >> 17], 1);
        csr_src[base + pos] = pv & 0x1FFFF;
    }
}

// ---------------- MFMA GEMM: hs(bf16) = (X @ W) * dinv[row] ----------------
template<int K, bool BF16IN>
__global__ __launch_bounds__(256) void gemm_bf16(const void* __restrict__ Xv,
                                                 const float* __restrict__ W,   // [K][64]
                                                 const float* __restrict__ dinv,
                                                 ushort* __restrict__ hs) {     // [N][64] bf16
    constexpr int KP = K + 8;
    __shared__ ushort A_lds[64][KP];
    __shared__ ushort Wt_lds[64][KP];
    int t = threadIdx.x;
    long row0 = (long)blockIdx.x * 64;

    for (int i = t; i < K * 16; i += 256) {
        float4 w4 = ((const float4*)W)[i];
        int k = i >> 4, n = (i & 15) * 4;
        Wt_lds[n + 0][k] = f2bf(w4.x);
        Wt_lds[n + 1][k] = f2bf(w4.y);
        Wt_lds[n + 2][k] = f2bf(w4.z);
        Wt_lds[n + 3][k] = f2bf(w4.w);
    }
    if (BF16IN) {
        constexpr int K2 = K / 2;
        const unsigned* X = (const unsigned*)Xv;
        for (int i = t; i < 64 * K2; i += 256) {
            int r = i / K2, c = i % K2;
            unsigned val = 0;
            long row = row0 + r;
            if (row < N_NODES) val = X[row * K2 + c];
            *(unsigned*)&A_lds[r][c * 2] = val;
        }
    } else {
        constexpr int K4 = K / 4;
        const float* X = (const float*)Xv;
        for (int i = t; i < 64 * K4; i += 256) {
            int r = i / K4, c = i % K4;
            float4 val = make_float4(0.f, 0.f, 0.f, 0.f);
            long row = row0 + r;
            if (row < N_NODES) val = ((const float4*)X)[row * K4 + c];
            int cb = c * 4;
            A_lds[r][cb + 0] = f2bf(val.x);
            A_lds[r][cb + 1] = f2bf(val.y);
            A_lds[r][cb + 2] = f2bf(val.z);
            A_lds[r][cb + 3] = f2bf(val.w);
        }
    }
    __syncthreads();

    int w = t >> 6, l = t & 63;
    int m = l & 15, quad = l >> 4;
    f32x4 acc[4];
#pragma unroll
    for (int c = 0; c < 4; c++) acc[c] = (f32x4){0.f, 0.f, 0.f, 0.f};

#pragma unroll
    for (int ch = 0; ch < K / 32; ch++) {
        short8 a = *(const short8*)&A_lds[16 * w + m][32 * ch + 8 * quad];
#pragma unroll
        for (int c = 0; c < 4; c++) {
            short8 b = *(const short8*)&Wt_lds[16 * c + m][32 * ch + 8 * quad];
            acc[c] = __builtin_amdgcn_mfma_f32_16x16x32_bf16(a, b, acc[c], 0, 0, 0);
        }
    }

#pragma unroll
    for (int r = 0; r < 4; r++) {
        long node = row0 + 16 * w + quad * 4 + r;
        if (node < N_NODES) {
            float dv = dinv[node];
#pragma unroll
            for (int c = 0; c < 4; c++)
                hs[node * 64 + 16 * c + m] = f2bf(acc[c][r] * dv);
        }
    }
}

// ---------------- pull-gather: dwordx4 row gathers + fused BN/ReLU ---------
// One wave per node. Lane l: edge-slot es = l>>3, feature-group fg = l&7
// (16 B = 8 bf16 features). One dwordx4 instr fetches 8 edges' chunks.
// Per-lane acc8 holds 8 feature partials; 3-round shfl_xor(8,16,32) tree
// produces full sums on all lanes. y written as packed bf16 uint4 (128 B).
template<bool LAST>
__global__ __launch_bounds__(256) void gather_feat(const int* __restrict__ row_ptr,
                                                   const int* __restrict__ csr_src,
                                                   const ushort* __restrict__ hs,
                                                   const float* __restrict__ dinv,
                                                   const float* __restrict__ b,
                                                   const float* __restrict__ g,
                                                   const float* __restrict__ beta,
                                                   const float* __restrict__ m,
                                                   const float* __restrict__ v,
                                                   unsigned* __restrict__ y,
                                                   const float* __restrict__ W3,
                                                   float* __restrict__ hs3, int n) {
    int i = (blockIdx.x * 256 + threadIdx.x) >> 6;
    if (i >= n) return;
    int l = threadIdx.x & 63;
    int es = l >> 3, fg = l & 7;
    const uint4* H4 = (const uint4*)hs;

    float a0 = 0.f, a1 = 0.f, a2 = 0.f, a3 = 0.f;
    float a4 = 0.f, a5 = 0.f, a6 = 0.f, a7 = 0.f;

    // self-loop: es==0 lanes cover the full row once
    if (es == 0) {
        uint4 p = H4[(long)i * 8 + fg];
        a0 += bf_lo(p.x); a1 += bf_hi(p.x);
        a2 += bf_lo(p.y); a3 += bf_hi(p.y);
        a4 += bf_lo(p.z); a5 += bf_hi(p.z);
        a6 += bf_lo(p.w); a7 += bf_hi(p.w);
    }

    int beg = row_ptr[i], end = row_ptr[i + 1];
    int k = beg;
    for (; k + 16 <= end; k += 16) {
        int sA = csr_src[k + es];
        int sB = csr_src[k + 8 + es];
        uint4 pA = H4[(long)sA * 8 + fg];
        uint4 pB = H4[(long)sB * 8 + fg];
        a0 += bf_lo(pA.x) + bf_lo(pB.x); a1 += bf_hi(pA.x) + bf_hi(pB.x);
        a2 += bf_lo(pA.y) + bf_lo(pB.y); a3 += bf_hi(pA.y) + bf_hi(pB.y);
        a4 += bf_lo(pA.z) + bf_lo(pB.z); a5 += bf_hi(pA.z) + bf_hi(pB.z);
        a6 += bf_lo(pA.w) + bf_lo(pB.w); a7 += bf_hi(pA.w) + bf_hi(pB.w);
    }
    for (; k + 8 <= end; k += 8) {
        int s = csr_src[k + es];
        uint4 p = H4[(long)s * 8 + fg];
        a0 += bf_lo(p.x); a1 += bf_hi(p.x);
        a2 += bf_lo(p.y); a3 += bf_hi(p.y);
        a4 += bf_lo(p.z); a5 += bf_hi(p.z);
        a6 += bf_lo(p.w); a7 += bf_hi(p.w);
    }
    int rem = end - k;
    if (es < rem) {
        int s = csr_src[k + es];
        uint4 p = H4[(long)s * 8 + fg];
        a0 += bf_lo(p.x); a1 += bf_hi(p.x);
        a2 += bf_lo(p.y); a3 += bf_hi(p.y);
        a4 += bf_lo(p.z); a5 += bf_hi(p.z);
        a6 += bf_lo(p.w); a7 += bf_hi(p.w);
    }

    // reduce across the 8 edge-slots (lanes with equal fg)
#pragma unroll
    for (int off = 8; off < 64; off <<= 1) {
        a0 += __shfl_xor(a0, off, 64);
        a1 += __shfl_xor(a1, off, 64);
        a2 += __shfl_xor(a2, off, 64);
        a3 += __shfl_xor(a3, off, 64);
        a4 += __shfl_xor(a4, off, 64);
        a5 += __shfl_xor(a5, off, 64);
        a6 += __shfl_xor(a6, off, 64);
        a7 += __shfl_xor(a7, off, 64);
    }

    // epilogue: this lane owns features fg*8 .. fg*8+7
    float4 bb0 = ((const float4*)b)[fg * 2],    bb1 = ((const float4*)b)[fg * 2 + 1];
    float4 gg0 = ((const float4*)g)[fg * 2],    gg1 = ((const float4*)g)[fg * 2 + 1];
    float4 be0 = ((const float4*)beta)[fg * 2], be1 = ((const float4*)beta)[fg * 2 + 1];
    float4 mm0 = ((const float4*)m)[fg * 2],    mm1 = ((const float4*)m)[fg * 2 + 1];
    float4 vv0 = ((const float4*)v)[fg * 2],    vv1 = ((const float4*)v)[fg * 2 + 1];
    float di = dinv[i];
    float o0 = fmaxf((di * a0 + bb0.x - mm0.x) * (gg0.x * rsqrtf(vv0.x + BN_EPS_)) + be0.x, 0.f);
    float o1 = fmaxf((di * a1 + bb0.y - mm0.y) * (gg0.y * rsqrtf(vv0.y + BN_EPS_)) + be0.y, 0.f);
    float o2 = fmaxf((di * a2 + bb0.z - mm0.z) * (gg0.z * rsqrtf(vv0.z + BN_EPS_)) + be0.z, 0.f);
    float o3 = fmaxf((di * a3 + bb0.w - mm0.w) * (gg0.w * rsqrtf(vv0.w + BN_EPS_)) + be0.w, 0.f);
    float o4 = fmaxf((di * a4 + bb1.x - mm1.x) * (gg1.x * rsqrtf(vv1.x + BN_EPS_)) + be1.x, 0.f);
    float o5 = fmaxf((di * a5 + bb1.y - mm1.y) * (gg1.y * rsqrtf(vv1.y + BN_EPS_)) + be1.y, 0.f);
    float o6 = fmaxf((di * a6 + bb1.z - mm1.z) * (gg1.z * rsqrtf(vv1.z + BN_EPS_)) + be1.z, 0.f);
    float o7 = fmaxf((di * a7 + bb1.w - mm1.w) * (gg1.w * rsqrtf(vv1.w + BN_EPS_)) + be1.w, 0.f);

    if (LAST) {
        float4 w30 = ((const float4*)W3)[fg * 2], w31 = ((const float4*)W3)[fg * 2 + 1];
        float p = o0 * w30.x + o1 * w30.y + o2 * w30.z + o3 * w30.w +
                  o4 * w31.x + o5 * w31.y + o6 * w31.z + o7 * w31.w;
#pragma unroll
        for (int off = 1; off < 8; off <<= 1)
            p += __shfl_xor(p, off, 64);
        if (l == 0) hs3[i] = p * di;
    } else {
        if (es == 0) {
            uint4 pk;
            pk.x = (unsigned)f2bf(o0) | ((unsigned)f2bf(o1) << 16);
            pk.y = (unsigned)f2bf(o2) | ((unsigned)f2bf(o3) << 16);
            pk.z = (unsigned)f2bf(o4) | ((unsigned)f2bf(o5) << 16);
            pk.w = (unsigned)f2bf(o6) | ((unsigned)f2bf(o7) << 16);
            ((uint4*)y)[(long)i * 8 + fg] = pk;
        }
    }
}

// ---------------- layer-3 pull + sigmoid (8 loads in flight) ----------------
__global__ __launch_bounds__(256) void gather3(const int* __restrict__ row_ptr,
                                               const int* __restrict__ csr_src,
                                               const float* __restrict__ hs3,
                                               const float* __restrict__ dinv,
                                               const float* __restrict__ b3,
                                               float* __restrict__ out, int n) {
    int i = blockIdx.x * 256 + threadIdx.x;
    if (i >= n) return;
    int beg = row_ptr[i], end = row_ptr[i + 1];
    float s0 = hs3[i], s1 = 0.f, s2 = 0.f, s3 = 0.f;
    float s4 = 0.f, s5 = 0.f, s6 = 0.f, s7 = 0.f;
    int k = beg;
    for (; k + 8 <= end; k += 8) {
        s0 += hs3[csr_src[k]];
        s1 += hs3[csr_src[k + 1]];
        s2 += hs3[csr_src[k + 2]];
        s3 += hs3[csr_src[k + 3]];
        s4 += hs3[csr_src[k + 4]];
        s5 += hs3[csr_src[k + 5]];
        s6 += hs3[csr_src[k + 6]];
        s7 += hs3[csr_src[k + 7]];
    }
    for (; k < end; k++) s0 += hs3[csr_src[k]];
    float z = dinv[i] * (((s0 + s1) + (s2 + s3)) + ((s4 + s5) + (s6 + s7))) + b3[0];
    out[i] = 1.f / (1.f + expf(-z));
}

extern "C" void kernel_launch(void* const* d_in, const int* in_sizes, int n_in,
                              void* d_out, int out_size, void* d_ws, size_t ws_size,
                              hipStream_t stream) {
    const int N = N_NODES;
    const int E = E_EDGES;

    const float* x   = (const float*)d_in[0];
    const int*   ei  = (const int*)d_in[1];   // [2, E]: row0=src, row1=dst
    const float* W1  = (const float*)d_in[2];
    const float* b1  = (const float*)d_in[3];
    const float* W2  = (const float*)d_in[4];
    const float* b2  = (const float*)d_in[5];
    const float* W3  = (const float*)d_in[6];
    const float* b3  = (const float*)d_in[7];
    const float* g1  = (const float*)d_in[8];
    const float* bt1 = (const float*)d_in[9];
    const float* m1  = (const float*)d_in[10];
    const float* v1  = (const float*)d_in[11];
    const float* g2  = (const float*)d_in[12];
    const float* bt2 = (const float*)d_in[13];
    const float* m2  = (const float*)d_in[14];
    const float* v2  = (const float*)d_in[15];
    float* out = (float*)d_out;

    // workspace layout (4-byte units)
    int*    wsi         = (int*)d_ws;
    float*  dinv        = (float*)wsi;                    // N
    float*  hs3         = (float*)(wsi + (long)N);        // N
    int*    row_ptr     = wsi + 2L * N;                   // N+1 (pad 16)
    int*    histPB      = wsi + 3L * N + 16;              // NBUCK*PB = 78200
    int*    bucket_tot  = histPB + NBUCK * PB;            // NBUCK (pad 400)
    int*    bucket_base = bucket_tot + 400;               // NBUCK+1 (pad 400)
    int*    csr_src     = bucket_base + 400;              // E
    ushort* hsb         = (ushort*)(csr_src + (long)E);   // N*64 bf16 (16B-aligned)
    unsigned* yb        = (unsigned*)(csr_src + (long)E + 32L * N); // N*32 uints
    int*    ebuf        = (int*)hsb;                      // E ints, aliases hsb

    // ---- CSR build (bucketed counting sort) ----
    passA1_hist<<<PB, 256, 0, stream>>>(ei, histPB);
    scan_rows<<<NBUCK, 256, 0, stream>>>(histPB, bucket_tot);
    scan_totals<<<1, 512, 0, stream>>>(bucket_tot, bucket_base, row_ptr);
    passA2_scatter<<<PB, 256, 0, stream>>>(ei, histPB, bucket_base, ebuf);
    passB_place<<<NBUCK, 256, 0, stream>>>(ebuf, bucket_base, row_ptr, csr_src, dinv);

    // ---- layer 1 ----
    gemm_bf16<IN_DIM_, false><<<(N + 63) / 64, 256, 0, stream>>>(x, W1, dinv, hsb);
    gather_feat<false><<<N / 4, 256, 0, stream>>>(row_ptr, csr_src, hsb, dinv,
                                                  b1, g1, bt1, m1, v1, yb, W3, hs3, N);
    // ---- layer 2 (+ fused gemv3) ----
    gemm_bf16<HID_, true><<<(N + 63) / 64, 256, 0, stream>>>(yb, W2, dinv, hsb);
    gather_feat<true><<<N / 4, 256, 0, stream>>>(row_ptr, csr_src, hsb, dinv,
                                                 b2, g2, bt2, m2, v2, yb, W3, hs3, N);
    // ---- layer 3 ----
    gather3<<<(N + 255) / 256, 256, 0, stream>>>(row_ptr, csr_src, hs3, dinv, b3, out, N);
}

// Round 11
// 430.796 us; speedup vs baseline: 6.8105x; 1.0030x over previous
//
#include <hip/hip_runtime.h>
#include <math.h>

#define N_NODES 100000
#define E_EDGES 3200000
#define IN_DIM_ 128
#define HID_ 64
#define BN_EPS_ 1e-5f

#define PB 200          // edge-chunk blocks
#define CHUNK 16000     // E / PB exactly
#define NBUCK 391       // ceil(N / 256): bucket = dst >> 8
#define BMAX 9600       // passB LDS sort capacity (mean 8184, 15 sigma)

typedef __attribute__((ext_vector_type(8))) short short8;
typedef __attribute__((ext_vector_type(4))) float f32x4;

__device__ inline ushort f2bf(float f) {
    union { float f; unsigned u; } c; c.f = f;
    unsigned r = c.u + 0x7fff + ((c.u >> 16) & 1);   // RNE
    return (ushort)(r >> 16);
}
__device__ inline float bf_lo(unsigned p) { union { unsigned u; float f; } c; c.u = p << 16; return c.f; }
__device__ inline float bf_hi(unsigned p) { union { unsigned u; float f; } c; c.u = p & 0xffff0000u; return c.f; }

// ---------------- pass A1: per-block bucket histogram ----------------
__global__ __launch_bounds__(256) void passA1_hist(const int* __restrict__ ei,
                                                   int* __restrict__ histPB) {
    __shared__ int hist[NBUCK];
    int t = threadIdx.x, b = blockIdx.x;
    for (int k = t; k < NBUCK; k += 256) hist[k] = 0;
    __syncthreads();
    int e0 = b * CHUNK, e1 = e0 + CHUNK;
    for (int e = e0 + t; e < e1; e += 256) {
        int d = ei[E_EDGES + e];
        atomicAdd(&hist[d >> 8], 1);
    }
    __syncthreads();
    for (int k = t; k < NBUCK; k += 256) histPB[k * PB + b] = hist[k];
}

// ---------------- per-bucket row scan ----------------
__global__ __launch_bounds__(256) void scan_rows(int* __restrict__ histPB,
                                                 int* __restrict__ bucket_tot) {
    __shared__ int wsum[4];
    int k = blockIdx.x, t = threadIdx.x, lane = t & 63, wv = t >> 6;
    int v = (t < PB) ? histPB[k * PB + t] : 0;
    int s = v;
#pragma unroll
    for (int off = 1; off < 64; off <<= 1) {
        int u = __shfl_up(s, off, 64);
        if (lane >= off) s += u;
    }
    if (lane == 63) wsum[wv] = s;
    __syncthreads();
    int wbase = 0;
    for (int w = 0; w < wv; w++) wbase += wsum[w];
    if (t < PB) histPB[k * PB + t] = wbase + s - v;
    if (t == 255) bucket_tot[k] = wbase + s;
}

// ---------------- scan bucket totals -> bucket_base ----------------
__global__ __launch_bounds__(512) void scan_totals(const int* __restrict__ bucket_tot,
                                                   int* __restrict__ bucket_base,
                                                   int* __restrict__ row_ptr) {
    __shared__ int wsum[8];
    int t = threadIdx.x, lane = t & 63, wv = t >> 6;
    int v = (t < NBUCK) ? bucket_tot[t] : 0;
    int s = v;
#pragma unroll
    for (int off = 1; off < 64; off <<= 1) {
        int u = __shfl_up(s, off, 64);
        if (lane >= off) s += u;
    }
    if (lane == 63) wsum[wv] = s;
    __syncthreads();
    int wbase = 0;
    for (int w = 0; w < wv; w++) wbase += wsum[w];
    if (t < NBUCK) bucket_base[t] = wbase + s - v;
    if (t == 0) {
        bucket_base[NBUCK] = E_EDGES;
        row_ptr[N_NODES] = E_EDGES;
    }
}

// ---- pass A2: LDS counting sort per chunk -> COALESCED ebuf writes ----
__global__ __launch_bounds__(256) void passA2_sorted(const int* __restrict__ ei,
                                                     const int* __restrict__ histPB,
                                                     const int* __restrict__ bucket_base,
                                                     int* __restrict__ ebuf) {
    __shared__ int sorted[CHUNK];     // 64 KB
    __shared__ ushort bid[CHUNK];     // 32 KB
    __shared__ int cur[NBUCK];
    __shared__ int lbase[NBUCK];
    int t = threadIdx.x, b = blockIdx.x;
    for (int k = t; k < NBUCK; k += 256) cur[k] = 0;
    __syncthreads();
    int e0 = b * CHUNK;
    // (a) local histogram
    for (int e = e0 + t; e < e0 + CHUNK; e += 256)
        atomicAdd(&cur[ei[E_EDGES + e] >> 8], 1);
    __syncthreads();
    // (b) exclusive scan cur -> lbase (single wave, chunks of 64)
    if (t < 64) {
        int run = 0;
        for (int c0 = 0; c0 < NBUCK; c0 += 64) {
            int idx = c0 + t;
            int v = (idx < NBUCK) ? cur[idx] : 0;
            int s = v;
#pragma unroll
            for (int off = 1; off < 64; off <<= 1) {
                int u = __shfl_up(s, off, 64);
                if (t >= off) s += u;
            }
            if (idx < NBUCK) lbase[idx] = run + s - v;
            run += __shfl(s, 63, 64);
        }
    }
    __syncthreads();
    for (int k = t; k < NBUCK; k += 256) cur[k] = lbase[k];
    __syncthreads();
    // (c) place into LDS (re-read ei; L2-hot)
    for (int e = e0 + t; e < e0 + CHUNK; e += 256) {
        int s = ei[e];
        int d = ei[E_EDGES + e];
        int k = d >> 8;
        int pos = atomicAdd(&cur[k], 1);
        sorted[pos] = s | ((d & 255) << 17);
        bid[pos] = (ushort)k;
    }
    __syncthreads();
    // (d) coalesced write-out (runs are contiguous per bucket)
    for (int j = t; j < CHUNK; j += 256) {
        int k = bid[j];
        int dest = bucket_base[k] + histPB[k * PB + b] + (j - lbase[k]);
        ebuf[dest] = sorted[j];
    }
}

// ---- pass B: LDS sort per bucket -> COALESCED csr writes + row_ptr + dinv ----
__global__ __launch_bounds__(256) void passB_sorted(const int* __restrict__ ebuf,
                                                    const int* __restrict__ bucket_base,
                                                    int* __restrict__ row_ptr,
                                                    int* __restrict__ csr_src,
                                                    float* __restrict__ dinv) {
    __shared__ int sorted[BMAX];      // 38.4 KB
    __shared__ int hist[256];
    __shared__ int wsum[4];
    int b = blockIdx.x, t = threadIdx.x, lane = t & 63, wv = t >> 6;
    int base = bucket_base[b], end = bucket_base[b + 1];
    hist[t] = 0;
    __syncthreads();
    for (int k = base + t; k < end; k += 256)
        atomicAdd(&hist[ebuf[k] >> 17], 1);
    __syncthreads();
    int v = hist[t];
    int s = v;
#pragma unroll
    for (int off = 1; off < 64; off <<= 1) {
        int u = __shfl_up(s, off, 64);
        if (lane >= off) s += u;
    }
    if (lane == 63) wsum[wv] = s;
    __syncthreads();
    int wbase = 0;
    for (int w = 0; w < wv; w++) wbase += wsum[w];
    int excl = wbase + s - v;
    int node = b * 256 + t;
    if (node < N_NODES) {
        row_ptr[node] = base + excl;
        dinv[node] = rsqrtf((float)v + 1.0f);
    }
    __syncthreads();
    hist[t] = excl;  // reuse as cursor
    __syncthreads();
    for (int k = base + t; k < end; k += 256) {
        int pv = ebuf[k];
        int pos = atomicAdd(&hist[pv >> 17], 1);
        if (pos < BMAX) sorted[pos] = pv;
        else csr_src[base + pos] = pv & 0x1FFFF;   // overflow safety valve
    }
    __syncthreads();
    int cnt = end - base;
    if (cnt > BMAX) cnt = BMAX;
    for (int j = t; j < cnt; j += 256)
        csr_src[base + j] = sorted[j] & 0x1FFFF;
}

// ---------------- MFMA GEMM: hs(bf16) = (X @ W) * dinv[row] ----------------
template<int K, bool BF16IN>
__global__ __launch_bounds__(256) void gemm_bf16(const void* __restrict__ Xv,
                                                 const float* __restrict__ W,   // [K][64]
                                                 const float* __restrict__ dinv,
                                                 ushort* __restrict__ hs) {     // [N][64] bf16
    constexpr int KP = K + 8;
    __shared__ ushort A_lds[64][KP];
    __shared__ ushort Wt_lds[64][KP];
    int t = threadIdx.x;
    long row0 = (long)blockIdx.x * 64;

    for (int i = t; i < K * 16; i += 256) {
        float4 w4 = ((const float4*)W)[i];
        int k = i >> 4, n = (i & 15) * 4;
        Wt_lds[n + 0][k] = f2bf(w4.x);
        Wt_lds[n + 1][k] = f2bf(w4.y);
        Wt_lds[n + 2][k] = f2bf(w4.z);
        Wt_lds[n + 3][k] = f2bf(w4.w);
    }
    if (BF16IN) {
        constexpr int K2 = K / 2;
        const unsigned* X = (const unsigned*)Xv;
        for (int i = t; i < 64 * K2; i += 256) {
            int r = i / K2, c = i % K2;
            unsigned val = 0;
            long row = row0 + r;
            if (row < N_NODES) val = X[row * K2 + c];
            *(unsigned*)&A_lds[r][c * 2] = val;
        }
    } else {
        constexpr int K4 = K / 4;
        const float* X = (const float*)Xv;
        for (int i = t; i < 64 * K4; i += 256) {
            int r = i / K4, c = i % K4;
            float4 val = make_float4(0.f, 0.f, 0.f, 0.f);
            long row = row0 + r;
            if (row < N_NODES) val = ((const float4*)X)[row * K4 + c];
            int cb = c * 4;
            A_lds[r][cb + 0] = f2bf(val.x);
            A_lds[r][cb + 1] = f2bf(val.y);
            A_lds[r][cb + 2] = f2bf(val.z);
            A_lds[r][cb + 3] = f2bf(val.w);
        }
    }
    __syncthreads();

    int w = t >> 6, l = t & 63;
    int m = l & 15, quad = l >> 4;
    f32x4 acc[4];
#pragma unroll
    for (int c = 0; c < 4; c++) acc[c] = (f32x4){0.f, 0.f, 0.f, 0.f};

#pragma unroll
    for (int ch = 0; ch < K / 32; ch++) {
        short8 a = *(const short8*)&A_lds[16 * w + m][32 * ch + 8 * quad];
#pragma unroll
        for (int c = 0; c < 4; c++) {
            short8 b = *(const short8*)&Wt_lds[16 * c + m][32 * ch + 8 * quad];
            acc[c] = __builtin_amdgcn_mfma_f32_16x16x32_bf16(a, b, acc[c], 0, 0, 0);
        }
    }

#pragma unroll
    for (int r = 0; r < 4; r++) {
        long node = row0 + 16 * w + quad * 4 + r;
        if (node < N_NODES) {
            float dv = dinv[node];
#pragma unroll
            for (int c = 0; c < 4; c++)
                hs[node * 64 + 16 * c + m] = f2bf(acc[c][r] * dv);
        }
    }
}

// ---------------- pull-gather: dwordx4 row gathers + fused BN/ReLU ---------
template<bool LAST>
__global__ __launch_bounds__(256) void gather_feat(const int* __restrict__ row_ptr,
                                                   const int* __restrict__ csr_src,
                                                   const ushort* __restrict__ hs,
                                                   const float* __restrict__ dinv,
                                                   const float* __restrict__ b,
                                                   const float* __restrict__ g,
                                                   const float* __restrict__ beta,
                                                   const float* __restrict__ m,
                                                   const float* __restrict__ v,
                                                   unsigned* __restrict__ y,
                                                   const float* __restrict__ W3,
                                                   float* __restrict__ hs3, int n) {
    int i = (blockIdx.x * 256 + threadIdx.x) >> 6;
    if (i >= n) return;
    int l = threadIdx.x & 63;
    int es = l >> 3, fg = l & 7;
    const uint4* H4 = (const uint4*)hs;

    float a0 = 0.f, a1 = 0.f, a2 = 0.f, a3 = 0.f;
    float a4 = 0.f, a5 = 0.f, a6 = 0.f, a7 = 0.f;

    if (es == 0) {   // self-loop
        uint4 p = H4[(long)i * 8 + fg];
        a0 += bf_lo(p.x); a1 += bf_hi(p.x);
        a2 += bf_lo(p.y); a3 += bf_hi(p.y);
        a4 += bf_lo(p.z); a5 += bf_hi(p.z);
        a6 += bf_lo(p.w); a7 += bf_hi(p.w);
    }

    int beg = row_ptr[i], end = row_ptr[i + 1];
    int k = beg;
    for (; k + 16 <= end; k += 16) {
        int sA = csr_src[k + es];
        int sB = csr_src[k + 8 + es];
        uint4 pA = H4[(long)sA * 8 + fg];
        uint4 pB = H4[(long)sB * 8 + fg];
        a0 += bf_lo(pA.x) + bf_lo(pB.x); a1 += bf_hi(pA.x) + bf_hi(pB.x);
        a2 += bf_lo(pA.y) + bf_lo(pB.y); a3 += bf_hi(pA.y) + bf_hi(pB.y);
        a4 += bf_lo(pA.z) + bf_lo(pB.z); a5 += bf_hi(pA.z) + bf_hi(pB.z);
        a6 += bf_lo(pA.w) + bf_lo(pB.w); a7 += bf_hi(pA.w) + bf_hi(pB.w);
    }
    for (; k + 8 <= end; k += 8) {
        int s = csr_src[k + es];
        uint4 p = H4[(long)s * 8 + fg];
        a0 += bf_lo(p.x); a1 += bf_hi(p.x);
        a2 += bf_lo(p.y); a3 += bf_hi(p.y);
        a4 += bf_lo(p.z); a5 += bf_hi(p.z);
        a6 += bf_lo(p.w); a7 += bf_hi(p.w);
    }
    int rem = end - k;
    if (es < rem) {
        int s = csr_src[k + es];
        uint4 p = H4[(long)s * 8 + fg];
        a0 += bf_lo(p.x); a1 += bf_hi(p.x);
        a2 += bf_lo(p.y); a3 += bf_hi(p.y);
        a4 += bf_lo(p.z); a5 += bf_hi(p.z);
        a6 += bf_lo(p.w); a7 += bf_hi(p.w);
    }

#pragma unroll
    for (int off = 8; off < 64; off <<= 1) {
        a0 += __shfl_xor(a0, off, 64);
        a1 += __shfl_xor(a1, off, 64);
        a2 += __shfl_xor(a2, off, 64);
        a3 += __shfl_xor(a3, off, 64);
        a4 += __shfl_xor(a4, off, 64);
        a5 += __shfl_xor(a5, off, 64);
        a6 += __shfl_xor(a6, off, 64);
        a7 += __shfl_xor(a7, off, 64);
    }

    float4 bb0 = ((const float4*)b)[fg * 2],    bb1 = ((const float4*)b)[fg * 2 + 1];
    float4 gg0 = ((const float4*)g)[fg * 2],    gg1 = ((const float4*)g)[fg * 2 + 1];
    float4 be0 = ((const float4*)beta)[fg * 2], be1 = ((const float4*)beta)[fg * 2 + 1];
    float4 mm0 = ((const float4*)m)[fg * 2],    mm1 = ((const float4*)m)[fg * 2 + 1];
    float4 vv0 = ((const float4*)v)[fg * 2],    vv1 = ((const float4*)v)[fg * 2 + 1];
    float di = dinv[i];
    float o0 = fmaxf((di * a0 + bb0.x - mm0.x) * (gg0.x * rsqrtf(vv0.x + BN_EPS_)) + be0.x, 0.f);
    float o1 = fmaxf((di * a1 + bb0.y - mm0.y) * (gg0.y * rsqrtf(vv0.y + BN_EPS_)) + be0.y, 0.f);
    float o2 = fmaxf((di * a2 + bb0.z - mm0.z) * (gg0.z * rsqrtf(vv0.z + BN_EPS_)) + be0.z, 0.f);
    float o3 = fmaxf((di * a3 + bb0.w - mm0.w) * (gg0.w * rsqrtf(vv0.w + BN_EPS_)) + be0.w, 0.f);
    float o4 = fmaxf((di * a4 + bb1.x - mm1.x) * (gg1.x * rsqrtf(vv1.x + BN_EPS_)) + be1.x, 0.f);
    float o5 = fmaxf((di * a5 + bb1.y - mm1.y) * (gg1.y * rsqrtf(vv1.y + BN_EPS_)) + be1.y, 0.f);
    float o6 = fmaxf((di * a6 + bb1.z - mm1.z) * (gg1.z * rsqrtf(vv1.z + BN_EPS_)) + be1.z, 0.f);
    float o7 = fmaxf((di * a7 + bb1.w - mm1.w) * (gg1.w * rsqrtf(vv1.w + BN_EPS_)) + be1.w, 0.f);

    if (LAST) {
        float4 w30 = ((const float4*)W3)[fg * 2], w31 = ((const float4*)W3)[fg * 2 + 1];
        float p = o0 * w30.x + o1 * w30.y + o2 * w30.z + o3 * w30.w +
                  o4 * w31.x + o5 * w31.y + o6 * w31.z + o7 * w31.w;
#pragma unroll
        for (int off = 1; off < 8; off <<= 1)
            p += __shfl_xor(p, off, 64);
        if (l == 0) hs3[i] = p * di;
    } else {
        if (es == 0) {
            uint4 pk;
            pk.x = (unsigned)f2bf(o0) | ((unsigned)f2bf(o1) << 16);
            pk.y = (unsigned)f2bf(o2) | ((unsigned)f2bf(o3) << 16);
            pk.z = (unsigned)f2bf(o4) | ((unsigned)f2bf(o5) << 16);
            pk.w = (unsigned)f2bf(o6) | ((unsigned)f2bf(o7) << 16);
            ((uint4*)y)[(long)i * 8 + fg] = pk;
        }
    }
}

// ---------------- layer-3 pull + sigmoid (8 loads in flight) ----------------
__global__ __launch_bounds__(256) void gather3(const int* __restrict__ row_ptr,
                                               const int* __restrict__ csr_src,
                                               const float* __restrict__ hs3,
                                               const float* __restrict__ dinv,
                                               const float* __restrict__ b3,
                                               float* __restrict__ out, int n) {
    int i = blockIdx.x * 256 + threadIdx.x;
    if (i >= n) return;
    int beg = row_ptr[i], end = row_ptr[i + 1];
    float s0 = hs3[i], s1 = 0.f, s2 = 0.f, s3 = 0.f;
    float s4 = 0.f, s5 = 0.f, s6 = 0.f, s7 = 0.f;
    int k = beg;
    for (; k + 8 <= end; k += 8) {
        s0 += hs3[csr_src[k]];
        s1 += hs3[csr_src[k + 1]];
        s2 += hs3[csr_src[k + 2]];
        s3 += hs3[csr_src[k + 3]];
        s4 += hs3[csr_src[k + 4]];
        s5 += hs3[csr_src[k + 5]];
        s6 += hs3[csr_src[k + 6]];
        s7 += hs3[csr_src[k + 7]];
    }
    for (; k < end; k++) s0 += hs3[csr_src[k]];
    float z = dinv[i] * (((s0 + s1) + (s2 + s3)) + ((s4 + s5) + (s6 + s7))) + b3[0];
    out[i] = 1.f / (1.f + expf(-z));
}

extern "C" void kernel_launch(void* const* d_in, const int* in_sizes, int n_in,
                              void* d_out, int out_size, void* d_ws, size_t ws_size,
                              hipStream_t stream) {
    const int N = N_NODES;
    const int E = E_EDGES;

    const float* x   = (const float*)d_in[0];
    const int*   ei  = (const int*)d_in[1];   // [2, E]: row0=src, row1=dst
    const float* W1  = (const float*)d_in[2];
    const float* b1  = (const float*)d_in[3];
    const float* W2  = (const float*)d_in[4];
    const float* b2  = (const float*)d_in[5];
    const float* W3  = (const float*)d_in[6];
    const float* b3  = (const float*)d_in[7];
    const float* g1  = (const float*)d_in[8];
    const float* bt1 = (const float*)d_in[9];
    const float* m1  = (const float*)d_in[10];
    const float* v1  = (const float*)d_in[11];
    const float* g2  = (const float*)d_in[12];
    const float* bt2 = (const float*)d_in[13];
    const float* m2  = (const float*)d_in[14];
    const float* v2  = (const float*)d_in[15];
    float* out = (float*)d_out;

    // workspace layout (4-byte units)
    int*    wsi         = (int*)d_ws;
    float*  dinv        = (float*)wsi;                    // N
    float*  hs3         = (float*)(wsi + (long)N);        // N
    int*    row_ptr     = wsi + 2L * N;                   // N+1 (pad 16)
    int*    histPB      = wsi + 3L * N + 16;              // NBUCK*PB = 78200
    int*    bucket_tot  = histPB + NBUCK * PB;            // NBUCK (pad 400)
    int*    bucket_base = bucket_tot + 400;               // NBUCK+1 (pad 400)
    int*    csr_src     = bucket_base + 400;              // E
    ushort* hsb         = (ushort*)(csr_src + (long)E);   // N*64 bf16 (16B-aligned)
    unsigned* yb        = (unsigned*)(csr_src + (long)E + 32L * N); // N*32 uints
    int*    ebuf        = (int*)hsb;                      // E ints, aliases hsb

    // ---- CSR build (bucketed counting sort, coalesced writes) ----
    passA1_hist<<<PB, 256, 0, stream>>>(ei, histPB);
    scan_rows<<<NBUCK, 256, 0, stream>>>(histPB, bucket_tot);
    scan_totals<<<1, 512, 0, stream>>>(bucket_tot, bucket_base, row_ptr);
    passA2_sorted<<<PB, 256, 0, stream>>>(ei, histPB, bucket_base, ebuf);
    passB_sorted<<<NBUCK, 256, 0, stream>>>(ebuf, bucket_base, row_ptr, csr_src, dinv);

    // ---- layer 1 ----
    gemm_bf16<IN_DIM_, false><<<(N + 63) / 64, 256, 0, stream>>>(x, W1, dinv, hsb);
    gather_feat<false><<<N / 4, 256, 0, stream>>>(row_ptr, csr_src, hsb, dinv,
                                                  b1, g1, bt1, m1, v1, yb, W3, hs3, N);
    // ---- layer 2 (+ fused gemv3) ----
    gemm_bf16<HID_, true><<<(N + 63) / 64, 256, 0, stream>>>(yb, W2, dinv, hsb);
    gather_feat<true><<<N / 4, 256, 0, stream>>>(row_ptr, csr_src, hsb, dinv,
                                                 b2, g2, bt2, m2, v2, yb, W3, hs3, N);
    // ---- layer 3 ----
    gather3<<<(N + 255) / 256, 256, 0, stream>>>(row_ptr, csr_src, hs3, dinv, b3, out, N);
}